// Round 1
// baseline (86.582 us; speedup 1.0000x reference)
//
#include <hip/hip_runtime.h>

#define B_DIM 512
#define D_DIM 512
#define O_DIM 512

// Tile: 64 b x 64 o x 64 d per block. Grid 8*8*8 = 512 blocks, 256 threads (4 waves).
// Wave w handles o-subrange [w*16, w*16+16), lane = local b index.
// logits[b,o] = sum_d ( (-ic)*x^2 + (2*mu*ic)*x ) + (-sum_d mu^2*ic), accumulated
// across 8 d-split blocks via fp32 atomicAdd into memset-zeroed d_out.

__global__ __launch_bounds__(256, 2)
void gaussianDA_kernel(const float* __restrict__ x,
                       const float* __restrict__ mu,
                       const float* __restrict__ ic,
                       float* __restrict__ out) {
    // interleaved (a', bb') per (o,d): row o = 64 d-pairs = 128 floats (512 B, 16B-aligned rows)
    __shared__ float lds_ab[64 * 64 * 2];     // 32 KB ; reused as transpose buffer in epilogue
    __shared__ float lds_x[64 * 65];          // [b][d], +1 pad: bank = (b + d) % 32 -> 2-way free
    __shared__ float lds_cp[64 * 17];         // staging partials of mu^2*ic per (o-row, seg)
    __shared__ float lds_c[64];               // -sum_{d in range} mu^2*ic per local o

    const int tid = threadIdx.x;
    const int bid = blockIdx.x;
    const int bb = bid & 7;                   // b-block 0..7
    const int ob = (bid >> 3) & 7;            // o-block 0..7
    const int ds = bid >> 6;                  // d-split 0..7
    const int b0 = bb * 64, o0 = ob * 64, d0 = ds * 64;

    // ---------------- stage: fused transform (a' = -ic, bb' = 2*mu*ic) ----------------
    const int seg = tid & 15;                 // 16 segs * 4 floats = 64 d
    const int row4 = tid >> 4;                // 0..15
#pragma unroll
    for (int k = 0; k < 4; ++k) {
        const int r = row4 + 16 * k;          // 0..63
        const int gcol = d0 + seg * 4;
        // o-operand tile (coalesced 16B loads)
        const float4 m4 = *(const float4*)&mu[(o0 + r) * D_DIM + gcol];
        const float4 c4 = *(const float4*)&ic[(o0 + r) * D_DIM + gcol];
        float4 w0, w1;
        w0.x = -c4.x; w0.y = 2.0f * m4.x * c4.x;
        w0.z = -c4.y; w0.w = 2.0f * m4.y * c4.y;
        w1.x = -c4.z; w1.y = 2.0f * m4.z * c4.z;
        w1.z = -c4.w; w1.w = 2.0f * m4.w * c4.w;
        *(float4*)&lds_ab[(r * 64 + seg * 4) * 2]     = w0;
        *(float4*)&lds_ab[(r * 64 + seg * 4) * 2 + 4] = w1;
        lds_cp[r * 17 + seg] = m4.x * m4.x * c4.x + m4.y * m4.y * c4.y
                             + m4.z * m4.z * c4.z + m4.w * m4.w * c4.w;
        // x tile (coalesced load, scalar LDS writes -> 2-way-free banks at stride 65)
        const float4 x4 = *(const float4*)&x[(b0 + r) * D_DIM + gcol];
        float* xr = &lds_x[r * 65 + seg * 4];
        xr[0] = x4.x; xr[1] = x4.y; xr[2] = x4.z; xr[3] = x4.w;
    }
    __syncthreads();

    // ---------------- per-o constant partial: -sum_d mu^2*ic over this d-range ----------------
    if (tid < 64) {
        float s = 0.0f;
#pragma unroll
        for (int j = 0; j < 16; ++j) s += lds_cp[tid * 17 + j];
        lds_c[tid] = -s;
    }

    // ---------------- main compute: lane = b, broadcast o-data, 2 fma per (o,d) ----------------
    const int w = tid >> 6;                   // wave id 0..3
    const int lane = tid & 63;                // local b
    float acc[16];
#pragma unroll
    for (int i = 0; i < 16; ++i) acc[i] = 0.0f;

#pragma unroll
    for (int half = 0; half < 2; ++half) {
        float xv[32], xs[32];
#pragma unroll
        for (int j = 0; j < 32; ++j) {
            xv[j] = lds_x[lane * 65 + half * 32 + j];
            xs[j] = xv[j] * xv[j];
        }
#pragma unroll
        for (int oi = 0; oi < 16; ++oi) {
            // row base: ((w*16+oi)*64 + half*32) pairs -> byte offset multiple of 16: ok for float4
            const float4* ab = (const float4*)&lds_ab[((w * 16 + oi) * 64 + half * 32) * 2];
            float a = acc[oi];
#pragma unroll
            for (int q = 0; q < 16; ++q) {     // each float4 = (a',bb') for 2 consecutive d
                const float4 t = ab[q];        // wave-uniform address -> LDS broadcast
                a = fmaf(t.x, xs[2 * q],     a);
                a = fmaf(t.y, xv[2 * q],     a);
                a = fmaf(t.z, xs[2 * q + 1], a);
                a = fmaf(t.w, xv[2 * q + 1], a);
            }
            acc[oi] = a;
        }
    }
    __syncthreads();   // all ab/x reads done; lds_c ready

    // ---------------- epilogue: transpose through LDS so atomics are coalesced on o ----------------
    float* tbuf = &lds_ab[w * 1040];          // per-wave [16 o][65] region (4160 B), within 32 KB
#pragma unroll
    for (int oi = 0; oi < 16; ++oi) tbuf[oi * 65 + lane] = acc[oi];
    __syncthreads();

    const int o_loc = lane & 15;
    const int bq = lane >> 4;                 // 0..3
    const float cadd = lds_c[w * 16 + o_loc];
    const int o_glob = o0 + w * 16 + o_loc;
#pragma unroll
    for (int k = 0; k < 16; ++k) {
        const int b_loc = bq * 16 + k;
        const float v = tbuf[o_loc * 65 + b_loc] + cadd;
        atomicAdd(&out[(b0 + b_loc) * O_DIM + o_glob], v);
    }
}

extern "C" void kernel_launch(void* const* d_in, const int* in_sizes, int n_in,
                              void* d_out, int out_size, void* d_ws, size_t ws_size,
                              hipStream_t stream) {
    const float* x  = (const float*)d_in[0];
    const float* mu = (const float*)d_in[1];
    const float* ic = (const float*)d_in[2];
    float* out = (float*)d_out;

    hipMemsetAsync(out, 0, (size_t)B_DIM * O_DIM * sizeof(float), stream);
    gaussianDA_kernel<<<dim3(512), dim3(256), 0, stream>>>(x, mu, ic, out);
}

// Round 2
// 74.028 us; speedup vs baseline: 1.1696x; 1.1696x over previous
//
#include <hip/hip_runtime.h>

#define B_DIM 512
#define D_DIM 512
#define O_DIM 512
#define KSPLIT 8
#define DCHUNK 64   // D_DIM / KSPLIT

// logits[b,o] = sum_d [ (-ic)*x^2 + (2*mu*ic)*x ] + (-sum_d mu^2*ic)
// Main: grid 512 = (ks 0..7)x(ob 0..7)x(bb 0..7); block 64b x 64o x 64d,
// 256 threads (4 waves of 32b x 32o), 4x4 register micro-tile per lane.
// Partials -> ws[block][64][64]; reduce kernel sums the 8 K-splits.
// No atomics, no memset, fully deterministic.

__global__ __launch_bounds__(256, 2)
void gda_main(const float* __restrict__ x,
              const float* __restrict__ mu,
              const float* __restrict__ ic,
              float* __restrict__ ws) {
    __shared__ float4 lds_x4[64 * 16];        // [b][g ^ (b&7)]      16 KB
    __shared__ float4 lds_ab4[64 * 16 * 2];   // [o][g ^ (o&7)][a,b] 32 KB
    __shared__ float  lds_cp[64 * 16];        // mu^2*ic partials     4 KB
    __shared__ float  lds_c[64];              // -sum over this d-range

    const int tid = threadIdx.x;
    const int bid = blockIdx.x;
    const int bb = bid & 7, ob = (bid >> 3) & 7, ks = bid >> 6;
    const int b0 = bb * 64, o0 = ob * 64, d0 = ks * DCHUNK;

    // ---- stage: coalesced global loads, fused transform, XOR-swizzled LDS ----
    const int g   = tid & 15;                 // float4 index within 64-d row
    const int row = tid >> 4;                 // 0..15
#pragma unroll
    for (int i = 0; i < 4; ++i) {
        const int r = row + 16 * i;           // 0..63
        const int sw = g ^ (r & 7);
        const float4 xv = *(const float4*)&x [(b0 + r) * D_DIM + d0 + g * 4];
        lds_x4[r * 16 + sw] = xv;
        const float4 m4 = *(const float4*)&mu[(o0 + r) * D_DIM + d0 + g * 4];
        const float4 c4 = *(const float4*)&ic[(o0 + r) * D_DIM + d0 + g * 4];
        float4 a4, b4;
        a4.x = -c4.x;            a4.y = -c4.y;
        a4.z = -c4.z;            a4.w = -c4.w;
        b4.x = 2.0f * m4.x * c4.x; b4.y = 2.0f * m4.y * c4.y;
        b4.z = 2.0f * m4.z * c4.z; b4.w = 2.0f * m4.w * c4.w;
        lds_ab4[(r * 16 + sw) * 2 + 0] = a4;
        lds_ab4[(r * 16 + sw) * 2 + 1] = b4;
        lds_cp[r * 16 + g] = m4.x * m4.x * c4.x + m4.y * m4.y * c4.y
                           + m4.z * m4.z * c4.z + m4.w * m4.w * c4.w;
    }
    __syncthreads();

    // per-o constant for this d-range (read after the 2nd barrier)
    if (tid < 64) {
        float s = 0.0f;
#pragma unroll
        for (int q = 0; q < 16; ++q) s += lds_cp[tid * 16 + q];
        lds_c[tid] = -s;
    }

    // ---- compute: 4 waves of 32b x 32o, 4x4 micro-tile per lane ----
    const int w    = tid >> 6;
    const int lane = tid & 63;
    const int cb   = lane >> 3;               // b-sub 0..7
    const int r8   = lane & 7;                // o-sub 0..7
    const int wb   = (w & 1) * 32, wo = (w >> 1) * 32;

    float acc[16];
#pragma unroll
    for (int q = 0; q < 16; ++q) acc[q] = 0.0f;

#pragma unroll
    for (int gg = 0; gg < 16; ++gg) {
        float4 xr[4], xs[4];
#pragma unroll
        for (int k = 0; k < 4; ++k) {
            xr[k] = lds_x4[(wb + cb + 8 * k) * 16 + (gg ^ cb)];
            xs[k].x = xr[k].x * xr[k].x;
            xs[k].y = xr[k].y * xr[k].y;
            xs[k].z = xr[k].z * xr[k].z;
            xs[k].w = xr[k].w * xr[k].w;
        }
#pragma unroll
        for (int j = 0; j < 4; ++j) {
            const int oo = wo + r8 + 8 * j;
            const float4 a4 = lds_ab4[(oo * 16 + (gg ^ r8)) * 2 + 0];
            const float4 b4 = lds_ab4[(oo * 16 + (gg ^ r8)) * 2 + 1];
#pragma unroll
            for (int k = 0; k < 4; ++k) {
                float t = acc[k * 4 + j];
                t = fmaf(a4.x, xs[k].x, t);  t = fmaf(b4.x, xr[k].x, t);
                t = fmaf(a4.y, xs[k].y, t);  t = fmaf(b4.y, xr[k].y, t);
                t = fmaf(a4.z, xs[k].z, t);  t = fmaf(b4.z, xr[k].z, t);
                t = fmaf(a4.w, xs[k].w, t);  t = fmaf(b4.w, xr[k].w, t);
                acc[k * 4 + j] = t;
            }
        }
    }
    __syncthreads();                          // lds_c now safe to read

    // ---- epilogue: partials (+ per-o constant) to workspace ----
    float* wsb = (float*)ws + (size_t)bid * 4096;
#pragma unroll
    for (int j = 0; j < 4; ++j) {
        const float cc = lds_c[wo + r8 + 8 * j];
#pragma unroll
        for (int k = 0; k < 4; ++k)
            wsb[(wb + cb + 8 * k) * 64 + (wo + r8 + 8 * j)] = acc[k * 4 + j] + cc;
    }
}

__global__ __launch_bounds__(256, 4)
void gda_reduce(const float* __restrict__ ws, float* __restrict__ out) {
    const int t0 = blockIdx.x * 1024 + threadIdx.x;
#pragma unroll
    for (int p = 0; p < 4; ++p) {
        const int flat = t0 + p * 256;
        const int b = flat >> 9, o = flat & 511;
        const int bb = b >> 6, bl = b & 63, ob = o >> 6, ol = o & 63;
        const float* base = ws + ((ob * 8 + bb) * 4096 + bl * 64 + ol);
        float s = 0.0f;
#pragma unroll
        for (int k = 0; k < KSPLIT; ++k) s += base[k * (64 * 4096)];
        out[flat] = s;
    }
}

extern "C" void kernel_launch(void* const* d_in, const int* in_sizes, int n_in,
                              void* d_out, int out_size, void* d_ws, size_t ws_size,
                              hipStream_t stream) {
    const float* x  = (const float*)d_in[0];
    const float* mu = (const float*)d_in[1];
    const float* ic = (const float*)d_in[2];
    float* ws  = (float*)d_ws;
    float* out = (float*)d_out;

    gda_main  <<<dim3(512), dim3(256), 0, stream>>>(x, mu, ic, ws);
    gda_reduce<<<dim3(256), dim3(256), 0, stream>>>(ws, out);
}